// Round 1
// baseline (187.693 us; speedup 1.0000x reference)
//
#include <hip/hip_runtime.h>
#include <math.h>

#define HH 256
#define WW 512
#define HWN (HH * WW)          // 131072
#define NPR 512
#define NSR 8
#define CHUNK 512              // HWN / 256 threads

// Kernel 1: pack direction map + env intensity into float4 {dx,dy,dz,intens}
__global__ void pack_kernel(const float* __restrict__ envs,
                            const float* __restrict__ dirmap,
                            float4* __restrict__ packed) {
    int n = blockIdx.x * blockDim.x + threadIdx.x;
    if (n >= HWN) return;
    float ex = envs[3 * n + 0];
    float ey = envs[3 * n + 1];
    float ez = envs[3 * n + 2];
    float inten = sqrtf(ex * ex + ey * ey + ez * ez);
    float dx = dirmap[3 * n + 0];
    float dy = dirmap[3 * n + 1];
    float dz = dirmap[3 * n + 2];
    packed[n] = make_float4(dx, dy, dz, inten);
}

// Kernel 2: one block per primary ray.
// Phase 1: 256 threads each sum a 512-elem chunk (fp64), LDS inclusive prefix.
// Phase 2: each of 4 waves handles 2 samples: binary-search chunk, one-wave
//          rescan of the chunk with shuffle scan to find the sampled index.
__global__ __launch_bounds__(256)
void sample_kernel(const float* __restrict__ normal,
                   const float4* __restrict__ packed,
                   const float* __restrict__ ps,
                   float* __restrict__ out) {
    const int p = blockIdx.x;
    const int t = threadIdx.x;

    // rotated normal: rotz = I (angle 0), rot = [[1,0,0],[0,0,-1],[0,-1,0]]
    // normal_r = (nx, -nz, -ny)
    const float nx = normal[3 * p + 0];
    const float ny = normal[3 * p + 1];
    const float nz = normal[3 * p + 2];
    const float rx = nx;
    const float ry = -nz;
    const float rz = -ny;

    __shared__ double pref[256];   // inclusive prefix of chunk sums
    __shared__ double s_total;

    // ---- Phase 1: chunk sums ----
    double csum = 0.0;
    const int base = t * CHUNK;
#pragma unroll 4
    for (int i = 0; i < CHUNK; ++i) {
        float4 d = packed[base + i];
        float m = rx * d.x + ry * d.y + rz * d.z;
        m = fminf(fmaxf(m, 0.0f), 1.0f);
        csum += (double)(d.w * m);
    }
    pref[t] = csum;
    __syncthreads();
    if (t == 0) {
        double run = 0.0;
        for (int i = 0; i < 256; ++i) { run += pref[i]; pref[i] = run; }
        s_total = run;
    }
    __syncthreads();

    const double total = s_total;
    const float totalF = (float)total;
    const float px = 2.0f / (float)HWN;

    const int wave = t >> 6;
    const int lane = t & 63;

    // ---- Phase 2: each wave processes samples (wave) and (wave+4) ----
    for (int si = 0; si < 2; ++si) {
        const int s = wave + si * 4;
        const double target = (double)ps[p * NSR + s] * total;

        // first chunk c with pref[c] > target  (wave-uniform binary search)
        int lo = 0, hi = 256;
        while (lo < hi) {
            int mid = (lo + hi) >> 1;
            if (pref[mid] > target) hi = mid; else lo = mid + 1;
        }
        const int c = lo;

        if (c >= 256) {
            // target >= total (rounding edge): clipped choice = HWN-1
            if (lane == 0) {
                int ch = HWN - 1;
                float4 d = packed[ch];
                float m = rx * d.x + ry * d.y + rz * d.z;
                m = fminf(fmaxf(m, 0.0f), 1.0f);
                float modu = d.w * m;
                float qx = modu / totalF + 1e-7f;
                float ratio = px * m / qx;
                int o = p * NSR + s;
                out[o] = (float)(ch / WW);
                out[NPR * NSR + o] = (float)(ch % WW);
                out[2 * NPR * NSR + o] = ratio;
            }
            continue;
        }

        const double basePref = (c > 0) ? pref[c - 1] : 0.0;
        const int cbase = c * CHUNK;
        const int n0 = cbase + lane * 8;

        float mvals[8];   // modulated
        float modv[8];    // mod
        double lsum = 0.0;
#pragma unroll
        for (int j = 0; j < 8; ++j) {
            float4 d = packed[n0 + j];
            float m = rx * d.x + ry * d.y + rz * d.z;
            m = fminf(fmaxf(m, 0.0f), 1.0f);
            modv[j] = m;
            mvals[j] = d.w * m;
            lsum += (double)mvals[j];
        }

        // inclusive shuffle scan of lane sums over 64 lanes, then exclusive
        double sc = lsum;
#pragma unroll
        for (int off = 1; off < 64; off <<= 1) {
            double v = __shfl_up(sc, off);
            if (lane >= off) sc += v;
        }
        double cum = basePref + (sc - lsum);

        int myidx = HWN;
        float mymod = 0.0f, mymodu = 0.0f;
#pragma unroll
        for (int j = 0; j < 8; ++j) {
            cum += (double)mvals[j];
            if (cum > target) { myidx = n0 + j; mymod = modv[j]; mymodu = mvals[j]; break; }
        }

        // min-index reduce over the wave, carrying payload
        int widx = myidx;
        float wmod = mymod, wmodu = mymodu;
#pragma unroll
        for (int off = 32; off > 0; off >>= 1) {
            int oi = __shfl_down(widx, off);
            float om = __shfl_down(wmod, off);
            float ou = __shfl_down(wmodu, off);
            if (oi < widx) { widx = oi; wmod = om; wmodu = ou; }
        }

        if (lane == 0) {
            int ch = widx;
            if (ch >= HWN) {
                // rounding edge: no element in chunk exceeded target; take chunk end
                ch = cbase + CHUNK - 1;
                float4 d = packed[ch];
                float m = rx * d.x + ry * d.y + rz * d.z;
                m = fminf(fmaxf(m, 0.0f), 1.0f);
                wmod = m;
                wmodu = d.w * m;
            }
            float qx = wmodu / totalF + 1e-7f;
            float ratio = px * wmod / qx;
            int o = p * NSR + s;
            out[o] = (float)(ch / WW);
            out[NPR * NSR + o] = (float)(ch % WW);
            out[2 * NPR * NSR + o] = ratio;
        }
    }
}

extern "C" void kernel_launch(void* const* d_in, const int* in_sizes, int n_in,
                              void* d_out, int out_size, void* d_ws, size_t ws_size,
                              hipStream_t stream) {
    const float* normal  = (const float*)d_in[0];
    const float* envs    = (const float*)d_in[1];
    const float* dirmap  = (const float*)d_in[2];
    const float* ps      = (const float*)d_in[3];
    // d_in[4] = env_idxs; NUM_ENVS == 1 so every index is 0 — env 0 used directly.
    float* out = (float*)d_out;
    float4* packed = (float4*)d_ws;   // HWN * 16 B = 2 MiB scratch

    pack_kernel<<<HWN / 256, 256, 0, stream>>>(envs, dirmap, packed);
    sample_kernel<<<NPR, 256, 0, stream>>>(normal, packed, ps, out);
}

// Round 2
// 93.366 us; speedup vs baseline: 2.0103x; 2.0103x over previous
//
#include <hip/hip_runtime.h>
#include <math.h>

#define HH 256
#define WW 512
#define HWN (HH * WW)          // 131072
#define NPR 512
#define NSR 8
#define CHUNK 512              // elements per chunk (= one row)
#define NCHUNK 256             // HWN / CHUNK
#define RPB 8                  // rays per block (chunksum kernel)
#define CPB 4                  // chunks per block = waves per block

// ---------------- Kernel 1: pack {dir.xyz, ||env||} into float4 ----------------
// 4 elements per thread via float4 loads (12 floats = 3 x float4 per array).
__global__ __launch_bounds__(256)
void pack_kernel(const float4* __restrict__ envs4,
                 const float4* __restrict__ dir4,
                 float4* __restrict__ packed) {
    int q = blockIdx.x * blockDim.x + threadIdx.x;   // q in [0, HWN/4)
    float4 e0 = envs4[3 * q + 0], e1 = envs4[3 * q + 1], e2 = envs4[3 * q + 2];
    float4 d0 = dir4[3 * q + 0],  d1 = dir4[3 * q + 1],  d2 = dir4[3 * q + 2];
    float i0 = sqrtf(e0.x * e0.x + e0.y * e0.y + e0.z * e0.z);
    float i1 = sqrtf(e0.w * e0.w + e1.x * e1.x + e1.y * e1.y);
    float i2 = sqrtf(e1.z * e1.z + e1.w * e1.w + e2.x * e2.x);
    float i3 = sqrtf(e2.y * e2.y + e2.z * e2.z + e2.w * e2.w);
    packed[4 * q + 0] = make_float4(d0.x, d0.y, d0.z, i0);
    packed[4 * q + 1] = make_float4(d0.w, d1.x, d1.y, i1);
    packed[4 * q + 2] = make_float4(d1.z, d1.w, d2.x, i2);
    packed[4 * q + 3] = make_float4(d2.y, d2.z, d2.w, i3);
}

// ---------------- Kernel 2: chunk sums S[p][c], 8-ray reuse ----------------
// Block: 256 threads = 4 waves. Wave w -> chunk c0+w; block covers rays r0..r0+7.
// Lane i reads packed[c*512 + k*64 + i] (coalesced float4), accumulates 8 ray
// partials in fp32, then fp64 cross-lane reduction; lane 0 stores 8 doubles.
__global__ __launch_bounds__(256)
void chunksum_kernel(const float* __restrict__ normal,
                     const float4* __restrict__ packed,
                     double* __restrict__ S) {
    const int wave = threadIdx.x >> 6;
    const int lane = threadIdx.x & 63;
    const int c  = blockIdx.x * CPB + wave;
    const int r0 = blockIdx.y * RPB;

    float rx[RPB], ry[RPB], rz[RPB];
#pragma unroll
    for (int i = 0; i < RPB; ++i) {
        int r = r0 + i;
        rx[i] =  normal[3 * r + 0];
        ry[i] = -normal[3 * r + 2];
        rz[i] = -normal[3 * r + 1];
    }

    float acc[RPB];
#pragma unroll
    for (int i = 0; i < RPB; ++i) acc[i] = 0.0f;

    const int base = c * CHUNK + lane;
#pragma unroll
    for (int k = 0; k < CHUNK / 64; ++k) {
        float4 d = packed[base + k * 64];
#pragma unroll
        for (int i = 0; i < RPB; ++i) {
            float m = fmaf(rx[i], d.x, fmaf(ry[i], d.y, rz[i] * d.z));
            m = fminf(fmaxf(m, 0.0f), 1.0f);
            acc[i] = fmaf(d.w, m, acc[i]);
        }
    }

#pragma unroll
    for (int i = 0; i < RPB; ++i) {
        double a = (double)acc[i];
#pragma unroll
        for (int off = 32; off > 0; off >>= 1)
            a += __shfl_down(a, off);
        if (lane == 0) S[(r0 + i) * NCHUNK + c] = a;
    }
}

// ---------------- Kernel 3: per-ray CDF sampling ----------------
__global__ __launch_bounds__(256)
void sample_kernel(const float* __restrict__ normal,
                   const float4* __restrict__ packed,
                   const double* __restrict__ S,
                   const float* __restrict__ ps,
                   float* __restrict__ out) {
    const int p = blockIdx.x;
    const int t = threadIdx.x;
    const int wave = t >> 6;
    const int lane = t & 63;

    // normal_r = (nx, -nz, -ny)   (rotz = I at angle 0)
    const float nx = normal[3 * p + 0];
    const float ny = normal[3 * p + 1];
    const float nz = normal[3 * p + 2];
    const float rx = nx, ry = -nz, rz = -ny;

    __shared__ double pref[NCHUNK];  // inclusive prefix of chunk sums
    __shared__ double wsum[4];

    // parallel fp64 scan of the 256 chunk sums
    double v = S[p * NCHUNK + t];
    double sc = v;
#pragma unroll
    for (int off = 1; off < 64; off <<= 1) {
        double u = __shfl_up(sc, off);
        if (lane >= off) sc += u;
    }
    if (lane == 63) wsum[wave] = sc;
    __syncthreads();
    double add = 0.0;
    for (int w2 = 0; w2 < wave; ++w2) add += wsum[w2];
    pref[t] = sc + add;
    __syncthreads();

    const double total = pref[NCHUNK - 1];
    const float totalF = (float)total;
    const float px = 2.0f / (float)HWN;

    // each wave processes samples (wave) and (wave+4)
    for (int si = 0; si < 2; ++si) {
        const int s = wave + si * 4;
        const double target = (double)ps[p * NSR + s] * total;

        // first chunk c with pref[c] > target (wave-uniform binary search)
        int lo = 0, hi = NCHUNK;
        while (lo < hi) {
            int mid = (lo + hi) >> 1;
            if (pref[mid] > target) hi = mid; else lo = mid + 1;
        }
        const int c = lo;

        if (c >= NCHUNK) {
            if (lane == 0) {
                int ch = HWN - 1;
                float4 d = packed[ch];
                float m = fmaf(rx, d.x, fmaf(ry, d.y, rz * d.z));
                m = fminf(fmaxf(m, 0.0f), 1.0f);
                float modu = d.w * m;
                float qx = modu / totalF + 1e-7f;
                float ratio = px * m / qx;
                int o = p * NSR + s;
                out[o] = (float)(ch / WW);
                out[NPR * NSR + o] = (float)(ch % WW);
                out[2 * NPR * NSR + o] = ratio;
            }
            continue;
        }

        const double basePref = (c > 0) ? pref[c - 1] : 0.0;
        const int cbase = c * CHUNK;
        const int n0 = cbase + lane * 8;

        float mvals[8];
        float modv[8];
        double lsum = 0.0;
#pragma unroll
        for (int j = 0; j < 8; ++j) {
            float4 d = packed[n0 + j];
            float m = fmaf(rx, d.x, fmaf(ry, d.y, rz * d.z));
            m = fminf(fmaxf(m, 0.0f), 1.0f);
            modv[j] = m;
            mvals[j] = d.w * m;
            lsum += (double)mvals[j];
        }

        // exclusive shuffle scan of lane sums
        double sc2 = lsum;
#pragma unroll
        for (int off = 1; off < 64; off <<= 1) {
            double u = __shfl_up(sc2, off);
            if (lane >= off) sc2 += u;
        }
        double cum = basePref + (sc2 - lsum);

        int myidx = HWN;
        float mymod = 0.0f, mymodu = 0.0f;
#pragma unroll
        for (int j = 0; j < 8; ++j) {
            cum += (double)mvals[j];
            if (cum > target) { myidx = n0 + j; mymod = modv[j]; mymodu = mvals[j]; break; }
        }

        int widx = myidx;
        float wmod = mymod, wmodu = mymodu;
#pragma unroll
        for (int off = 32; off > 0; off >>= 1) {
            int oi = __shfl_down(widx, off);
            float om = __shfl_down(wmod, off);
            float ou = __shfl_down(wmodu, off);
            if (oi < widx) { widx = oi; wmod = om; wmodu = ou; }
        }

        if (lane == 0) {
            int ch = widx;
            if (ch >= HWN) {
                // rounding edge: no element exceeded target; take chunk end
                ch = cbase + CHUNK - 1;
                float4 d = packed[ch];
                float m = fmaf(rx, d.x, fmaf(ry, d.y, rz * d.z));
                m = fminf(fmaxf(m, 0.0f), 1.0f);
                wmod = m;
                wmodu = d.w * m;
            }
            float qx = wmodu / totalF + 1e-7f;
            float ratio = px * wmod / qx;
            int o = p * NSR + s;
            out[o] = (float)(ch / WW);
            out[NPR * NSR + o] = (float)(ch % WW);
            out[2 * NPR * NSR + o] = ratio;
        }
    }
}

extern "C" void kernel_launch(void* const* d_in, const int* in_sizes, int n_in,
                              void* d_out, int out_size, void* d_ws, size_t ws_size,
                              hipStream_t stream) {
    const float* normal  = (const float*)d_in[0];
    const float* envs    = (const float*)d_in[1];
    const float* dirmap  = (const float*)d_in[2];
    const float* ps      = (const float*)d_in[3];
    // d_in[4] = env_idxs; NUM_ENVS == 1 so every index is 0.
    float* out = (float*)d_out;

    float4* packed = (float4*)d_ws;                              // 2 MiB
    double* S      = (double*)((char*)d_ws + (size_t)HWN * 16);  // 1 MiB

    pack_kernel<<<HWN / 4 / 256, 256, 0, stream>>>(
        (const float4*)envs, (const float4*)dirmap, packed);
    chunksum_kernel<<<dim3(NCHUNK / CPB, NPR / RPB), 256, 0, stream>>>(
        normal, packed, S);
    sample_kernel<<<NPR, 256, 0, stream>>>(normal, packed, S, ps, out);
}

// Round 3
// 91.363 us; speedup vs baseline: 2.0544x; 1.0219x over previous
//
#include <hip/hip_runtime.h>
#include <math.h>

#define HH 256
#define WW 512
#define HWN (HH * WW)          // 131072
#define NPR 512
#define NSR 8
#define CHUNK 512              // elements per chunk (= one HDRI row)
#define NCHUNK 256             // HWN / CHUNK
#define RPB 16                 // rays per block (chunksum kernel)
#define CPB 4                  // chunks per block = waves per block

// Granule mapping: 4 consecutive elements <-> 3 float4 loads (12 floats).
// For granule base element b (b*3 % 4 == 0), lane l covers elems b+4l..b+4l+3
// via float4 indices (3*b/4 + 3l + {0,1,2}). Fully coalesced.
__device__ __forceinline__ void load_granule4(const float4* __restrict__ envs4,
                                              const float4* __restrict__ dir4,
                                              int f4base,
                                              float inten[4], float dx[4],
                                              float dy[4], float dz[4]) {
    float4 e0 = envs4[f4base + 0], e1 = envs4[f4base + 1], e2 = envs4[f4base + 2];
    float4 d0 = dir4[f4base + 0],  d1 = dir4[f4base + 1],  d2 = dir4[f4base + 2];
    inten[0] = sqrtf(e0.x * e0.x + e0.y * e0.y + e0.z * e0.z);
    inten[1] = sqrtf(e0.w * e0.w + e1.x * e1.x + e1.y * e1.y);
    inten[2] = sqrtf(e1.z * e1.z + e1.w * e1.w + e2.x * e2.x);
    inten[3] = sqrtf(e2.y * e2.y + e2.z * e2.z + e2.w * e2.w);
    dx[0] = d0.x; dy[0] = d0.y; dz[0] = d0.z;
    dx[1] = d0.w; dy[1] = d1.x; dz[1] = d1.y;
    dx[2] = d1.z; dy[2] = d1.w; dz[2] = d2.x;
    dx[3] = d2.y; dy[3] = d2.z; dz[3] = d2.w;
}

// ---------------- Kernel 1: chunk sums S[p][c], 16-ray reuse, raw inputs ----
__global__ __launch_bounds__(256)
void chunksum_kernel(const float* __restrict__ normal,
                     const float4* __restrict__ envs4,
                     const float4* __restrict__ dir4,
                     double* __restrict__ S) {
    const int wave = threadIdx.x >> 6;
    const int lane = threadIdx.x & 63;
    const int c  = blockIdx.x * CPB + wave;
    const int r0 = blockIdx.y * RPB;

    float rx[RPB], ry[RPB], rz[RPB];
#pragma unroll
    for (int i = 0; i < RPB; ++i) {
        int r = r0 + i;
        rx[i] =  normal[3 * r + 0];
        ry[i] = -normal[3 * r + 2];
        rz[i] = -normal[3 * r + 1];
    }

    float acc[RPB];
#pragma unroll
    for (int i = 0; i < RPB; ++i) acc[i] = 0.0f;

#pragma unroll
    for (int g = 0; g < 2; ++g) {
        const int f4base = c * 384 + g * 192 + 3 * lane;
        float inten[4], dx[4], dy[4], dz[4];
        load_granule4(envs4, dir4, f4base, inten, dx, dy, dz);
#pragma unroll
        for (int j = 0; j < 4; ++j) {
#pragma unroll
            for (int i = 0; i < RPB; ++i) {
                float m = fmaf(rx[i], dx[j], fmaf(ry[i], dy[j], rz[i] * dz[j]));
                m = fminf(fmaxf(m, 0.0f), 1.0f);
                acc[i] = fmaf(inten[j], m, acc[i]);
            }
        }
    }

#pragma unroll
    for (int i = 0; i < RPB; ++i) {
        double a = (double)acc[i];
#pragma unroll
        for (int off = 32; off > 0; off >>= 1)
            a += __shfl_down(a, off);
        if (lane == 0) S[(r0 + i) * NCHUNK + c] = a;
    }
}

// ---------------- Kernel 2: per-ray CDF sampling, raw inputs ----------------
__global__ __launch_bounds__(256)
void sample_kernel(const float* __restrict__ normal,
                   const float4* __restrict__ envs4,
                   const float4* __restrict__ dir4,
                   const double* __restrict__ S,
                   const float* __restrict__ ps,
                   float* __restrict__ out) {
    const int p = blockIdx.x;
    const int t = threadIdx.x;
    const int wave = t >> 6;
    const int lane = t & 63;
    const float* envs = (const float*)envs4;
    const float* dirm = (const float*)dir4;

    // normal_r = (nx, -nz, -ny)   (rotz = I at angle 0)
    const float rx =  normal[3 * p + 0];
    const float ry = -normal[3 * p + 2];
    const float rz = -normal[3 * p + 1];

    __shared__ double pref[NCHUNK];  // inclusive prefix of chunk sums
    __shared__ double wsum[4];

    // parallel fp64 scan of the 256 chunk sums
    double v = S[p * NCHUNK + t];
    double sc = v;
#pragma unroll
    for (int off = 1; off < 64; off <<= 1) {
        double u = __shfl_up(sc, off);
        if (lane >= off) sc += u;
    }
    if (lane == 63) wsum[wave] = sc;
    __syncthreads();
    double add = 0.0;
    for (int w2 = 0; w2 < wave; ++w2) add += wsum[w2];
    pref[t] = sc + add;
    __syncthreads();

    const double total = pref[NCHUNK - 1];
    const float totalF = (float)total;
    const float px = 2.0f / (float)HWN;

    // each wave processes samples (wave) and (wave+4)
    for (int si = 0; si < 2; ++si) {
        const int s = wave + si * 4;
        const double target = (double)ps[p * NSR + s] * total;

        // first chunk c with pref[c] > target (wave-uniform binary search)
        int lo = 0, hi = NCHUNK;
        while (lo < hi) {
            int mid = (lo + hi) >> 1;
            if (pref[mid] > target) hi = mid; else lo = mid + 1;
        }
        const int c = lo;

        if (c >= NCHUNK) {
            if (lane == 0) {
                int ch = HWN - 1;
                float ex = envs[3 * ch], ey = envs[3 * ch + 1], ez = envs[3 * ch + 2];
                float inten = sqrtf(ex * ex + ey * ey + ez * ez);
                float m = fmaf(rx, dirm[3 * ch], fmaf(ry, dirm[3 * ch + 1], rz * dirm[3 * ch + 2]));
                m = fminf(fmaxf(m, 0.0f), 1.0f);
                float modu = inten * m;
                float qx = modu / totalF + 1e-7f;
                float ratio = px * m / qx;
                int o = p * NSR + s;
                out[o] = (float)(ch / WW);
                out[NPR * NSR + o] = (float)(ch % WW);
                out[2 * NPR * NSR + o] = ratio;
            }
            continue;
        }

        const double basePref = (c > 0) ? pref[c - 1] : 0.0;
        const int cbase = c * CHUNK;

        // two granules of 4 consecutive elements per lane
        float mvals[8], modv[8];
        double lsum[2];
#pragma unroll
        for (int g = 0; g < 2; ++g) {
            const int f4base = c * 384 + g * 192 + 3 * lane;
            float inten[4], dx[4], dy[4], dz[4];
            load_granule4(envs4, dir4, f4base, inten, dx, dy, dz);
            double ls = 0.0;
#pragma unroll
            for (int j = 0; j < 4; ++j) {
                float m = fmaf(rx, dx[j], fmaf(ry, dy[j], rz * dz[j]));
                m = fminf(fmaxf(m, 0.0f), 1.0f);
                modv[4 * g + j] = m;
                mvals[4 * g + j] = inten[j] * m;
                ls += (double)mvals[4 * g + j];
            }
            lsum[g] = ls;
        }

        // inclusive shuffle scans per granule
        double s0 = lsum[0], s1 = lsum[1];
#pragma unroll
        for (int off = 1; off < 64; off <<= 1) {
            double u0 = __shfl_up(s0, off);
            double u1 = __shfl_up(s1, off);
            if (lane >= off) { s0 += u0; s1 += u1; }
        }
        const double g0tot = __shfl(s0, 63);
        const double cum0base = basePref + (s0 - lsum[0]);
        const double cum1base = basePref + g0tot + (s1 - lsum[1]);

        int myidx = HWN;
        float mymod = 0.0f, mymodu = 0.0f;
        double cum = cum0base;
#pragma unroll
        for (int j = 0; j < 4 && myidx == HWN; ++j) {
            cum += (double)mvals[j];
            if (cum > target) { myidx = cbase + 4 * lane + j; mymod = modv[j]; mymodu = mvals[j]; }
        }
        if (myidx == HWN) {
            cum = cum1base;
#pragma unroll
            for (int j = 0; j < 4 && myidx == HWN; ++j) {
                cum += (double)mvals[4 + j];
                if (cum > target) { myidx = cbase + 256 + 4 * lane + j; mymod = modv[4 + j]; mymodu = mvals[4 + j]; }
            }
        }

        // min-index reduce over the wave, carrying payload
        int widx = myidx;
        float wmod = mymod, wmodu = mymodu;
#pragma unroll
        for (int off = 32; off > 0; off >>= 1) {
            int oi = __shfl_down(widx, off);
            float om = __shfl_down(wmod, off);
            float ou = __shfl_down(wmodu, off);
            if (oi < widx) { widx = oi; wmod = om; wmodu = ou; }
        }

        if (lane == 0) {
            int ch = widx;
            if (ch >= HWN) {
                // rounding edge: no element exceeded target; take chunk end
                ch = cbase + CHUNK - 1;
                float ex = envs[3 * ch], ey = envs[3 * ch + 1], ez = envs[3 * ch + 2];
                float inten = sqrtf(ex * ex + ey * ey + ez * ez);
                float m = fmaf(rx, dirm[3 * ch], fmaf(ry, dirm[3 * ch + 1], rz * dirm[3 * ch + 2]));
                m = fminf(fmaxf(m, 0.0f), 1.0f);
                wmod = m;
                wmodu = inten * m;
            }
            float qx = wmodu / totalF + 1e-7f;
            float ratio = px * wmod / qx;
            int o = p * NSR + s;
            out[o] = (float)(ch / WW);
            out[NPR * NSR + o] = (float)(ch % WW);
            out[2 * NPR * NSR + o] = ratio;
        }
    }
}

extern "C" void kernel_launch(void* const* d_in, const int* in_sizes, int n_in,
                              void* d_out, int out_size, void* d_ws, size_t ws_size,
                              hipStream_t stream) {
    const float* normal  = (const float*)d_in[0];
    const float* envs    = (const float*)d_in[1];
    const float* dirmap  = (const float*)d_in[2];
    const float* ps      = (const float*)d_in[3];
    // d_in[4] = env_idxs; NUM_ENVS == 1 so every index is 0.
    float* out = (float*)d_out;

    double* S = (double*)d_ws;   // NPR * NCHUNK * 8 B = 1 MiB

    chunksum_kernel<<<dim3(NCHUNK / CPB, NPR / RPB), 256, 0, stream>>>(
        normal, (const float4*)envs, (const float4*)dirmap, S);
    sample_kernel<<<NPR, 256, 0, stream>>>(
        normal, (const float4*)envs, (const float4*)dirmap, S, ps, out);
}